// Round 3
// baseline (279.148 us; speedup 1.0000x reference)
//
#include <hip/hip_runtime.h>
#include <hip/hip_bf16.h>
#include <stdint.h>

// Problem: 3x Bahdanau attention (p/c/h heads) -> averaged softmax weights -> weighted sum of sentence.
// S=8192, H2=1024, A=2048, E=768. All inputs fp32; output fp32 [1024].
// R3: REGRESSED (memory-clobber on waitcnt asm -> compiler drained vmcnt(0); 84.9us).
// R4: 212.8us total; counted vmcnt(3) pipeline engaged: gemm 54.2us, occ 27%, but MfmaUtil only 16%
//     and bank conflicts UP (4.28M): ds_read row stride 64B -> 8-way conflict; 32x64 wave tile
//     reads 6KB LDS per 8 MFMA -> LDS-read-bound 2.4x even conflict-free.
// R5: (a) wave tile 64x64 (BM 128, 4x4 frags): halves LDS bytes per FLOP.
//     (b) XOR swizzle both-sides (rule #21): pre-swizzled global source chunk (tid&3)^(row&3),
//         linear gl_lds dest, swizzled ds_read slot quad^(row&3). 8-way -> 4-way conflict.
//     (c) no-atomic ctxb (full-E per block) + zero e_arr/out inside k_prep -> memset node gone.

namespace {

constexpr int S = 8192;
constexpr int H = 1024;   // H2
constexpr int A = 2048;
constexpr int E = 768;

typedef __bf16 bf16x8 __attribute__((ext_vector_type(8)));
typedef float f32x4 __attribute__((ext_vector_type(4)));

__device__ __forceinline__ void gl_lds16(const void* g, void* l) {
  __builtin_amdgcn_global_load_lds(
      (const __attribute__((address_space(1))) void*)g,
      (__attribute__((address_space(3))) void*)l, 16, 0, 0);
}

// ---------- merged prep ----------
// [0,4096)      cvt sentence->bf16 (only rows < round_up(len,128))
// [4096,5632)   transpose W_sent fp32 [H][A] -> bf16 [A][H]
// [5632,5656)   ctxb[head][a] = ctx @ W_ctx + b_s + b_c   (24 blocks, full E loop, NO atomics)
// [5656,5664)   zero e_arr + out (replaces the memset dispatch)
__global__ __launch_bounds__(256)
void k_prep(const float* __restrict__ sentence, __bf16* __restrict__ sentB,
            const float* __restrict__ Wp, const float* __restrict__ Wc_s,
            const float* __restrict__ Wh, __bf16* __restrict__ WtB,
            const float* __restrict__ ctx_p, const float* __restrict__ ctx_c,
            const float* __restrict__ ctx_h,
            const float* __restrict__ Wcx_p, const float* __restrict__ Wcx_c,
            const float* __restrict__ Wcx_h,
            const float* __restrict__ bs_p, const float* __restrict__ bs_c,
            const float* __restrict__ bs_h,
            const float* __restrict__ bc_p, const float* __restrict__ bc_c,
            const float* __restrict__ bc_h,
            float* __restrict__ ctxb, float* __restrict__ e_arr,
            const int* __restrict__ length, float* __restrict__ out, int n_out) {
  __shared__ float tile[64][65];
  int b = blockIdx.x;
  int t = threadIdx.x;

  if (b < 4096) {
    // ---- phase 1: sentence fp32 -> bf16, 8 elems/thread; 2 rows per block ----
    int len = min(max(length[0], 0), S);
    int lenp = (len + 127) & ~127;        // GEMM touches rows < round_up(len,128)
    if (b * 2 >= lenp) return;
    int g = b * 256 + t;
    const float4* s4 = (const float4*)sentence + (size_t)g * 2;
    float4 a = s4[0], c = s4[1];
    bf16x8 o;
    o[0] = (__bf16)a.x; o[1] = (__bf16)a.y; o[2] = (__bf16)a.z; o[3] = (__bf16)a.w;
    o[4] = (__bf16)c.x; o[5] = (__bf16)c.y; o[6] = (__bf16)c.z; o[7] = (__bf16)c.w;
    *((bf16x8*)sentB + g) = o;
  } else if (b < 5632) {
    // ---- phase 2: W_sent [H][A] fp32 -> Wt [A][H] bf16 ----
    int r = b - 4096;                 // 512 tiles per head
    int head = r >> 9; r &= 511;
    const float* W = head == 0 ? Wp : (head == 1 ? Wc_s : Wh);
    __bf16* dst = WtB + (size_t)head * A * H;
    int a0 = (r & 31) * 64;           // 32 a-tiles
    int k0 = (r >> 5) * 64;           // 16 k-tiles
#pragma unroll
    for (int i = 0; i < 16; ++i) {
      int idx = t + i * 256;
      int rr = idx >> 6, cc = idx & 63;
      tile[cc][rr] = W[(size_t)(k0 + rr) * A + a0 + cc];   // coalesced over cc
    }
    __syncthreads();
#pragma unroll
    for (int i = 0; i < 16; ++i) {
      int idx = t + i * 256;
      int al = idx >> 6, kl = idx & 63;
      dst[(size_t)(a0 + al) * H + k0 + kl] = (__bf16)tile[al][kl];  // coalesced over kl
    }
  } else if (b < 5656) {
    // ---- phase 3: ctxb[head][a] = ctx @ W_ctx + b_s + b_c, one block owns 256 a-values ----
    int r = b - 5632;                 // 24 blocks: 3 heads x 8 a-blocks
    int head = r >> 3;
    int ablk = r & 7;
    const float* ctx = head == 0 ? ctx_p : (head == 1 ? ctx_c : ctx_h);
    const float* Wc  = head == 0 ? Wcx_p : (head == 1 ? Wcx_c : Wcx_h);
    const float* bs  = head == 0 ? bs_p : (head == 1 ? bs_c : bs_h);
    const float* bc  = head == 0 ? bc_p : (head == 1 ? bc_c : bc_h);
    int a = ablk * 256 + t;
    float s = bs[a] + bc[a];
#pragma unroll 8
    for (int e = 0; e < E; ++e) s = fmaf(ctx[e], Wc[(size_t)e * A + a], s);
    ctxb[head * A + a] = s;           // direct store: no memset, no atomics
  } else {
    // ---- phase 4: zero e_arr (6144 float4) + out (n_out/4 float4) ----
    int idx = (b - 5656) * 256 + t;   // 8 blocks x 256 threads = 2048 strides
    float4 z = {0.f, 0.f, 0.f, 0.f};
    int total = 6144 + (n_out >> 2);
    for (int i = idx; i < total; i += 2048) {
      if (i < 6144) ((float4*)e_arr)[i] = z;
      else ((float4*)out)[i - 6144] = z;
    }
  }
}

// ---------- GEMM + fused tanh*v epilogue -> e[head][s] ----------
// 128x128 tile, 64x64 per wave (4x4 16x16x32 frags), BK=32, 3 LDS buffers, counted vmcnt(4).
// LDS swizzle (both-sides, rule #21): gl_lds dest linear; thread tid loads global 16B chunk
// (tid&3)^((tid>>2)&3) of its row; ds_read uses slot quad^(row&3). Row pitch 64B has only 2
// controllable slot bits -> residual 4-way conflict (was 8-way).
__global__ __launch_bounds__(256)
void k_gemm_e(const __bf16* __restrict__ sentB, const __bf16* __restrict__ WtB,
              const float* __restrict__ ctxb,
              const float* __restrict__ v_p, const float* __restrict__ v_c,
              const float* __restrict__ v_h,
              const int* __restrict__ length, float* __restrict__ e_out) {
  int m0 = blockIdx.x * 128;
  int len = min(max(length[0], 0), S);
  if (m0 >= len) return;          // masked rows can never influence the softmax
  int n0 = blockIdx.y * 128;
  int head = blockIdx.z;
  const float* v  = head == 0 ? v_p : (head == 1 ? v_c : v_h);
  const __bf16* Wt = WtB + (size_t)head * A * H;
  const float* cb = ctxb + head * A;
  float* e_h = e_out + head * S;

  __shared__ __align__(16) __bf16 lsA[3 * 4096];   // 3 bufs x [128 rows][32 k] (swizzled slots)
  __shared__ __align__(16) __bf16 lsB[3 * 4096];
  __shared__ float e_part[128];

  int tid = threadIdx.x;
  if (tid < 128) e_part[tid] = 0.f;   // visible well before epilogue (32 barriers intervene)

  int lane = tid & 63;
  int wave = tid >> 6;
  int wm = wave >> 1, wn = wave & 1;       // wave tile: 64 rows x 64 cols
  int quad = lane >> 4, l16 = lane & 15;
  int sw = (quad ^ (l16 & 3)) << 3;        // swizzled k-slot (elements) for ds_read

  f32x4 acc[4][4];
#pragma unroll
  for (int i = 0; i < 4; ++i)
#pragma unroll
    for (int j = 0; j < 4; ++j) acc[i][j] = (f32x4){0.f, 0.f, 0.f, 0.f};

  int srow = tid >> 2;                               // staging row within 64-row half
  int scol = ((tid & 3) ^ (srow & 3)) * 8;           // pre-swizzled global chunk
  const __bf16* gA0 = sentB + (size_t)(m0 + srow) * H + scol;
  const __bf16* gA1 = gA0 + (size_t)64 * H;
  const __bf16* gB0 = Wt + (size_t)(n0 + srow) * H + scol;
  const __bf16* gB1 = gB0 + (size_t)64 * H;

  // 4 vector-mem instructions per STAGE -> vmcnt(4) == "previous tile's stage complete".
#define STAGE(bufi, kk)                                           \
  do {                                                            \
    gl_lds16(gA0 + (kk), lsA + (bufi) * 4096 + tid * 8);          \
    gl_lds16(gA1 + (kk), lsA + (bufi) * 4096 + 2048 + tid * 8);   \
    gl_lds16(gB0 + (kk), lsB + (bufi) * 4096 + tid * 8);          \
    gl_lds16(gB1 + (kk), lsB + (bufi) * 4096 + 2048 + tid * 8);   \
  } while (0)

#define COMPUTE(bufi)                                                                           \
  do {                                                                                          \
    bf16x8 af[4], bfv[4];                                                                       \
    _Pragma("unroll")                                                                           \
    for (int i = 0; i < 4; ++i)                                                                 \
      af[i] = *(const bf16x8*)&lsA[(bufi) * 4096 + (wm * 64 + i * 16 + l16) * 32 + sw];         \
    _Pragma("unroll")                                                                           \
    for (int j = 0; j < 4; ++j)                                                                 \
      bfv[j] = *(const bf16x8*)&lsB[(bufi) * 4096 + (wn * 64 + j * 16 + l16) * 32 + sw];        \
    _Pragma("unroll")                                                                           \
    for (int i = 0; i < 4; ++i)                                                                 \
      _Pragma("unroll")                                                                         \
      for (int j = 0; j < 4; ++j)                                                               \
        acc[i][j] = __builtin_amdgcn_mfma_f32_16x16x32_bf16(af[i], bfv[j], acc[i][j], 0, 0, 0); \
  } while (0)

  // prologue: 2 tiles in flight
  STAGE(0, 0);
  STAGE(1, 32);
  int cur = 0, pf = 2;
#pragma unroll 1
  for (int t = 0; t < 31; ++t) {
    asm volatile("s_waitcnt vmcnt(4)");        // tile t landed (tile t+1's 4 stay in flight)
    __builtin_amdgcn_s_barrier();              // all waves' tile-t writes visible
    __builtin_amdgcn_sched_barrier(0);         // no ds_read hoists above this point
    if (t < 30) STAGE(pf, (t + 2) * 32);       // after barrier: WAR on buffer pf is safe
    COMPUTE(cur);
    cur = cur == 2 ? 0 : cur + 1;
    pf = pf == 2 ? 0 : pf + 1;
  }
  asm volatile("s_waitcnt vmcnt(0)");
  __builtin_amdgcn_s_barrier();
  __builtin_amdgcn_sched_barrier(0);
  COMPUTE(cur);   // tile 31

#undef STAGE
#undef COMPUTE

  float vj[4], cbj[4];
#pragma unroll
  for (int j = 0; j < 4; ++j) {
    int col = n0 + wn * 64 + j * 16 + l16;
    vj[j] = v[col];
    cbj[j] = cb[col];
  }
#pragma unroll
  for (int i = 0; i < 4; ++i) {
#pragma unroll
    for (int r = 0; r < 4; ++r) {
      float p = 0.f;
#pragma unroll
      for (int j = 0; j < 4; ++j) {
        float u = acc[i][j][r] + cbj[j];
        float ex = __expf(2.f * u);        // tanh = 1 - 2/(e^2x+1); inf-safe at both ends
        float th = 1.f - 2.f / (ex + 1.f);
        p = fmaf(th, vj[j], p);
      }
      p += __shfl_xor(p, 1);
      p += __shfl_xor(p, 2);
      p += __shfl_xor(p, 4);
      p += __shfl_xor(p, 8);
      if (l16 == 0) atomicAdd(&e_part[wm * 64 + i * 16 + quad * 4 + r], p);
    }
  }
  __syncthreads();
  if (tid < 128) atomicAdd(&e_h[m0 + tid], e_part[tid]);
}

// ---------- out[h] = sum_s w(s) * sentence[s][h]; softmax stats computed per block ----------
// Stats are redundant per block (e_arr is L2-resident) but remove the k_stats dispatch + edge.
__global__ void k_out(const float* __restrict__ sent, const float* __restrict__ e_arr,
                      const int* __restrict__ length, float* __restrict__ out) {
  int len = min(max(length[0], 0), S);
  int r0 = blockIdx.x * 16;
  if (r0 >= len) return;
  int tid = threadIdx.x;

  __shared__ float red[3][4];
  __shared__ float sstat[6];    // m0,s0,m1,s1,m2,s2
  __shared__ float wrow[16];

  // pass 1: per-head max over s < len
#pragma unroll
  for (int h = 0; h < 3; ++h) {
    const float* e_h = e_arr + h * S;
    float m = -3.4e38f;
    for (int s = tid; s < len; s += 256) m = fmaxf(m, e_h[s]);
#pragma unroll
    for (int o = 32; o >= 1; o >>= 1) m = fmaxf(m, __shfl_xor(m, o));
    if ((tid & 63) == 0) red[h][tid >> 6] = m;
  }
  __syncthreads();
  if (tid < 3) sstat[tid * 2] = fmaxf(fmaxf(red[tid][0], red[tid][1]),
                                      fmaxf(red[tid][2], red[tid][3]));
  __syncthreads();
  // pass 2: per-head sum of exp
#pragma unroll
  for (int h = 0; h < 3; ++h) {
    const float* e_h = e_arr + h * S;
    float mm = sstat[h * 2];
    float ss = 0.f;
    for (int s = tid; s < len; s += 256) ss += __expf(e_h[s] - mm);
#pragma unroll
    for (int o = 32; o >= 1; o >>= 1) ss += __shfl_xor(ss, o);
    if ((tid & 63) == 0) red[h][tid >> 6] = ss;
  }
  __syncthreads();
  if (tid < 3) sstat[tid * 2 + 1] = red[tid][0] + red[tid][1] + red[tid][2] + red[tid][3];
  __syncthreads();

  // fused weights for this block's rows (computed once, not per-thread)
  if (tid < 16 && r0 + tid < len) {
    int r = r0 + tid;
    wrow[tid] = (__expf(e_arr[r] - sstat[0]) / sstat[1] +
                 __expf(e_arr[S + r] - sstat[2]) / sstat[3] +
                 __expf(e_arr[2 * S + r] - sstat[4]) / sstat[5]) * (1.f / 3.f);
  }
  __syncthreads();

  int col = tid * 4;
  int rend = min(r0 + 16, len);
  float4 acc = {0.f, 0.f, 0.f, 0.f};
  for (int r = r0; r < rend; ++r) {
    float w = wrow[r - r0];
    float4 x = *(const float4*)(sent + (size_t)r * H + col);
    acc.x = fmaf(w, x.x, acc.x);
    acc.y = fmaf(w, x.y, acc.y);
    acc.z = fmaf(w, x.z, acc.z);
    acc.w = fmaf(w, x.w, acc.w);
  }
  atomicAdd(&out[col + 0], acc.x);
  atomicAdd(&out[col + 1], acc.y);
  atomicAdd(&out[col + 2], acc.z);
  atomicAdd(&out[col + 3], acc.w);
}

}  // namespace

extern "C" void kernel_launch(void* const* d_in, const int* in_sizes, int n_in,
                              void* d_out, int out_size, void* d_ws, size_t ws_size,
                              hipStream_t stream) {
  const float* sentence = (const float*)d_in[0];
  const int* length     = (const int*)d_in[1];
  const float* ctx_p = (const float*)d_in[2];
  const float* ctx_c = (const float*)d_in[3];
  const float* ctx_h = (const float*)d_in[4];
  const float* W_s[3] = {(const float*)d_in[5],  (const float*)d_in[11], (const float*)d_in[17]};
  const float* b_s[3] = {(const float*)d_in[6],  (const float*)d_in[12], (const float*)d_in[18]};
  const float* W_c[3] = {(const float*)d_in[7],  (const float*)d_in[13], (const float*)d_in[19]};
  const float* b_c[3] = {(const float*)d_in[8],  (const float*)d_in[14], (const float*)d_in[20]};
  const float* v_[3]  = {(const float*)d_in[9],  (const float*)d_in[15], (const float*)d_in[21]};
  float* out = (float*)d_out;

  // workspace layout (bytes)
  char* ws = (char*)d_ws;
  __bf16* sentB = (__bf16*)(ws);               // 8192*1024*2   = 16777216
  __bf16* WtB   = (__bf16*)(ws + 16777216);    // 3*2048*1024*2 = 12582912
  float* ctxb   = (float*)(ws + 29360128);     // 3*2048*4      = 24576
  float* e_arr  = (float*)(ws + 29384704);     // 3*8192*4      = 98304

  // no memsets: ctxb is direct-stored, e_arr/out zeroed inside k_prep (3 graph nodes total)
  k_prep<<<5664, 256, 0, stream>>>(sentence, sentB,
                                   W_s[0], W_s[1], W_s[2], WtB,
                                   ctx_p, ctx_c, ctx_h,
                                   W_c[0], W_c[1], W_c[2],
                                   b_s[0], b_s[1], b_s[2],
                                   b_c[0], b_c[1], b_c[2], ctxb, e_arr,
                                   length, out, out_size);
  k_gemm_e<<<dim3(S / 128, A / 128, 3), 256, 0, stream>>>(sentB, WtB, ctxb,
                                                          v_[0], v_[1], v_[2], length, e_arr);
  k_out<<<S / 16, 256, 0, stream>>>(sentence, e_arr, length, out);
}

// Round 4
// 251.453 us; speedup vs baseline: 1.1101x; 1.1101x over previous
//
#include <hip/hip_runtime.h>
#include <hip/hip_bf16.h>
#include <stdint.h>

// Problem: 3x Bahdanau attention (p/c/h heads) -> averaged softmax weights -> weighted sum of sentence.
// S=8192, H2=1024, A=2048, E=768. All inputs fp32; output fp32 [1024].
// R4: 212.8us total, gemm 54.2us (64x128 tile, 3-buf, counted vmcnt(3)) -- best so far.
// R5: REGRESSED 279us: (a) 128^2 tile halved TLP (720 blocks) and raised LDS bytes/iter -> 84.6us gemm,
//     counters identical to unswizzled R3 => the 2-bit swizzle at 64B pitch was a no-op;
//     (b) ctxb serialized to 24 blocks x 768 dependent loads -> +45us on the prep side.
// R6: (a) revert gemm to R4 shape (BM=64), deepen pipeline to 3 tiles in flight (4 bufs, vmcnt(6),
//         peeled 3-iter tail for exact counts);
//     (b) ctxb computed per-block in gemm prologue (L2-hot, overlaps prologue staging) -- prep
//         phase 3 deleted, no cross-kernel dependency, no atomics, no memset;
//     (c) k_prep = cvt + W-transpose + zero only.

namespace {

constexpr int S = 8192;
constexpr int H = 1024;   // H2
constexpr int A = 2048;
constexpr int E = 768;

typedef __bf16 bf16x8 __attribute__((ext_vector_type(8)));
typedef float f32x4 __attribute__((ext_vector_type(4)));

__device__ __forceinline__ void gl_lds16(const void* g, void* l) {
  __builtin_amdgcn_global_load_lds(
      (const __attribute__((address_space(1))) void*)g,
      (__attribute__((address_space(3))) void*)l, 16, 0, 0);
}

// ---------- merged prep ----------
// [0,4096)      cvt sentence->bf16 (only rows < round_up(len,64))
// [4096,5632)   transpose W_sent fp32 [H][A] -> bf16 [A][H]
// [5632,5640)   zero e_arr + out
__global__ __launch_bounds__(256)
void k_prep(const float* __restrict__ sentence, __bf16* __restrict__ sentB,
            const float* __restrict__ Wp, const float* __restrict__ Wc_s,
            const float* __restrict__ Wh, __bf16* __restrict__ WtB,
            float* __restrict__ e_arr,
            const int* __restrict__ length, float* __restrict__ out, int n_out) {
  __shared__ float tile[64][65];
  int b = blockIdx.x;
  int t = threadIdx.x;

  if (b < 4096) {
    // ---- phase 1: sentence fp32 -> bf16, 8 elems/thread; 2 rows per block ----
    int len = min(max(length[0], 0), S);
    int lenp = (len + 63) & ~63;          // GEMM touches rows < round_up(len,64)
    if (b * 2 >= lenp) return;
    int g = b * 256 + t;
    const float4* s4 = (const float4*)sentence + (size_t)g * 2;
    float4 a = s4[0], c = s4[1];
    bf16x8 o;
    o[0] = (__bf16)a.x; o[1] = (__bf16)a.y; o[2] = (__bf16)a.z; o[3] = (__bf16)a.w;
    o[4] = (__bf16)c.x; o[5] = (__bf16)c.y; o[6] = (__bf16)c.z; o[7] = (__bf16)c.w;
    *((bf16x8*)sentB + g) = o;
  } else if (b < 5632) {
    // ---- phase 2: W_sent [H][A] fp32 -> Wt [A][H] bf16 ----
    int r = b - 4096;                 // 512 tiles per head
    int head = r >> 9; r &= 511;
    const float* W = head == 0 ? Wp : (head == 1 ? Wc_s : Wh);
    __bf16* dst = WtB + (size_t)head * A * H;
    int a0 = (r & 31) * 64;           // 32 a-tiles
    int k0 = (r >> 5) * 64;           // 16 k-tiles
#pragma unroll
    for (int i = 0; i < 16; ++i) {
      int idx = t + i * 256;
      int rr = idx >> 6, cc = idx & 63;
      tile[cc][rr] = W[(size_t)(k0 + rr) * A + a0 + cc];   // coalesced over cc
    }
    __syncthreads();
#pragma unroll
    for (int i = 0; i < 16; ++i) {
      int idx = t + i * 256;
      int al = idx >> 6, kl = idx & 63;
      dst[(size_t)(a0 + al) * H + k0 + kl] = (__bf16)tile[al][kl];  // coalesced over kl
    }
  } else {
    // ---- phase 3: zero e_arr (6144 float4) + out ----
    int idx = (b - 5632) * 256 + t;   // 8 blocks x 256 threads = 2048 strides
    float4 z = {0.f, 0.f, 0.f, 0.f};
    int total = 6144 + (n_out >> 2);
    for (int i = idx; i < total; i += 2048) {
      if (i < 6144) ((float4*)e_arr)[i] = z;
      else ((float4*)out)[i - 6144] = z;
    }
  }
}

// ---------- GEMM + fused tanh*v epilogue -> e[head][s] ----------
// 64x128 tile, BK=32, 4 LDS buffers, 3 tiles in flight, counted vmcnt(6) (3 loads/stage).
// ctxb (ctx @ W_ctx + b_s + b_c for this block's 128 cols) computed in the prologue from
// L2-hot data, overlapping the initial staging. Raw s_barrier + clobber-free waitcnt asm
// + sched_barrier(0) (R3 lesson: a "memory" clobber forces a vmcnt(0) drain).
__global__ __launch_bounds__(256)
void k_gemm_e(const __bf16* __restrict__ sentB, const __bf16* __restrict__ WtB,
              const float* __restrict__ ctx_p, const float* __restrict__ ctx_c,
              const float* __restrict__ ctx_h,
              const float* __restrict__ Wcx_p, const float* __restrict__ Wcx_c,
              const float* __restrict__ Wcx_h,
              const float* __restrict__ bs_p, const float* __restrict__ bs_c,
              const float* __restrict__ bs_h,
              const float* __restrict__ bc_p, const float* __restrict__ bc_c,
              const float* __restrict__ bc_h,
              const float* __restrict__ v_p, const float* __restrict__ v_c,
              const float* __restrict__ v_h,
              const int* __restrict__ length, float* __restrict__ e_out) {
  int m0 = blockIdx.x * 64;
  int len = min(max(length[0], 0), S);
  if (m0 >= len) return;          // masked rows can never influence the softmax
  int n0 = blockIdx.y * 128;
  int head = blockIdx.z;
  const float* v  = head == 0 ? v_p : (head == 1 ? v_c : v_h);
  const __bf16* Wt = WtB + (size_t)head * A * H;
  float* e_h = e_out + head * S;

  __shared__ __align__(16) __bf16 lsA[4 * 2048];   // 4 bufs x [64 rows][32 k]
  __shared__ __align__(16) __bf16 lsB[4 * 4096];   // 4 bufs x [128 rows][32 k]
  __shared__ float cb_part[256];                   // 2 halves x 128 cols of ctx@Wc
  __shared__ float e_part[64];

  int tid = threadIdx.x;
  if (tid < 64) e_part[tid] = 0.f;   // wave-ordered LDS + 32 barriers before epilogue read

  int lane = tid & 63;
  int wave = tid >> 6;
  int wm = wave >> 1, wn = wave & 1;       // wave tile: 32 rows x 64 cols
  int quad = lane >> 4, l16 = lane & 15;

  f32x4 acc[2][4];
#pragma unroll
  for (int i = 0; i < 2; ++i)
#pragma unroll
    for (int j = 0; j < 4; ++j) acc[i][j] = (f32x4){0.f, 0.f, 0.f, 0.f};

  const __bf16* gA0 = sentB + (size_t)(m0 + (tid >> 2)) * H + ((tid & 3) * 8);
  const __bf16* gB0 = Wt + (size_t)(n0 + (tid >> 2)) * H + ((tid & 3) * 8);
  const __bf16* gB1 = gB0 + (size_t)64 * H;

  // 3 vector-mem instructions per STAGE -> steady-state wait vmcnt(6) = oldest tile landed.
#define STAGE(bufi, kk)                                           \
  do {                                                            \
    gl_lds16(gA0 + (kk), lsA + (bufi) * 2048 + tid * 8);          \
    gl_lds16(gB0 + (kk), lsB + (bufi) * 4096 + tid * 8);          \
    gl_lds16(gB1 + (kk), lsB + (bufi) * 4096 + 2048 + tid * 8);   \
  } while (0)

#define COMPUTE(bufi)                                                                          \
  do {                                                                                         \
    bf16x8 af[2], bfv[4];                                                                      \
    _Pragma("unroll")                                                                          \
    for (int i = 0; i < 2; ++i)                                                                \
      af[i] = *(const bf16x8*)&lsA[(bufi) * 2048 + (wm * 32 + i * 16 + l16) * 32 + quad * 8];  \
    _Pragma("unroll")                                                                          \
    for (int j = 0; j < 4; ++j)                                                                \
      bfv[j] = *(const bf16x8*)&lsB[(bufi) * 4096 + (wn * 64 + j * 16 + l16) * 32 + quad * 8]; \
    _Pragma("unroll")                                                                          \
    for (int i = 0; i < 2; ++i)                                                                \
      _Pragma("unroll")                                                                        \
      for (int j = 0; j < 4; ++j)                                                              \
        acc[i][j] = __builtin_amdgcn_mfma_f32_16x16x32_bf16(af[i], bfv[j], acc[i][j], 0, 0, 0);\
  } while (0)

  // prologue: 3 tiles in flight + ctxb for this block's 128 cols (overlaps staging latency).
  STAGE(0, 0);
  STAGE(1, 32);
  STAGE(2, 64);
  {
    const float* ctx = head == 0 ? ctx_p : (head == 1 ? ctx_c : ctx_h);
    const float* Wc  = head == 0 ? Wcx_p : (head == 1 ? Wcx_c : Wcx_h);
    int col = n0 + (tid & 127);
    int e0 = (tid >> 7) * (E / 2);
    float s = 0.f;
#pragma unroll 8
    for (int e = e0; e < e0 + E / 2; ++e) s = fmaf(ctx[e], Wc[(size_t)e * A + col], s);
    cb_part[tid] = s;
    // (compiler-inserted waits for Wc uses drain the staged gl_lds too -- benign: we want
    //  tiles 0-2 resident before iter 0 anyway; pipeline refills by iter 3.)
  }

#pragma unroll 1
  for (int t = 0; t < 29; ++t) {
    asm volatile("s_waitcnt vmcnt(6)");        // tile t landed (t+1, t+2 stay in flight)
    __builtin_amdgcn_s_barrier();              // all waves' tile-t writes visible
    __builtin_amdgcn_sched_barrier(0);         // no ds_read hoists above this point
    STAGE((t + 3) & 3, (t + 3) * 32);          // buf computed at iter t-1; barrier-protected
    COMPUTE(t & 3);
  }
  // peeled tail with exact counts: tiles 29 (6 left), 30 (3 left), 31 (0 left)
  asm volatile("s_waitcnt vmcnt(6)");
  __builtin_amdgcn_s_barrier();
  __builtin_amdgcn_sched_barrier(0);
  COMPUTE(1);
  asm volatile("s_waitcnt vmcnt(3)");
  __builtin_amdgcn_s_barrier();
  __builtin_amdgcn_sched_barrier(0);
  COMPUTE(2);
  asm volatile("s_waitcnt vmcnt(0)");
  __builtin_amdgcn_s_barrier();
  __builtin_amdgcn_sched_barrier(0);
  COMPUTE(3);

#undef STAGE
#undef COMPUTE

  const float* bs = head == 0 ? bs_p : (head == 1 ? bs_c : bs_h);
  const float* bc = head == 0 ? bc_p : (head == 1 ? bc_c : bc_h);
  float vj[4], cbj[4];
#pragma unroll
  for (int j = 0; j < 4; ++j) {
    int cl = wn * 64 + j * 16 + l16;
    int col = n0 + cl;
    vj[j] = v[col];
    cbj[j] = cb_part[cl] + cb_part[128 + cl] + bs[col] + bc[col];
  }
#pragma unroll
  for (int i = 0; i < 2; ++i) {
#pragma unroll
    for (int r = 0; r < 4; ++r) {
      float p = 0.f;
#pragma unroll
      for (int j = 0; j < 4; ++j) {
        float u = acc[i][j][r] + cbj[j];
        float ex = __expf(2.f * u);        // tanh = 1 - 2/(e^2x+1); inf-safe at both ends
        float th = 1.f - 2.f / (ex + 1.f);
        p = fmaf(th, vj[j], p);
      }
      p += __shfl_xor(p, 1);
      p += __shfl_xor(p, 2);
      p += __shfl_xor(p, 4);
      p += __shfl_xor(p, 8);
      if (l16 == 0) atomicAdd(&e_part[wm * 32 + i * 16 + quad * 4 + r], p);
    }
  }
  __syncthreads();
  if (tid < 64) atomicAdd(&e_h[m0 + tid], e_part[tid]);
}

// ---------- out[h] = sum_s w(s) * sentence[s][h]; softmax stats computed per block ----------
// Stats are redundant per block (e_arr is L2-resident) but remove a dispatch + edge.
__global__ void k_out(const float* __restrict__ sent, const float* __restrict__ e_arr,
                      const int* __restrict__ length, float* __restrict__ out) {
  int len = min(max(length[0], 0), S);
  int r0 = blockIdx.x * 16;
  if (r0 >= len) return;
  int tid = threadIdx.x;

  __shared__ float red[3][4];
  __shared__ float sstat[6];    // m0,s0,m1,s1,m2,s2
  __shared__ float wrow[16];

  // pass 1: per-head max over s < len
#pragma unroll
  for (int h = 0; h < 3; ++h) {
    const float* e_h = e_arr + h * S;
    float m = -3.4e38f;
    for (int s = tid; s < len; s += 256) m = fmaxf(m, e_h[s]);
#pragma unroll
    for (int o = 32; o >= 1; o >>= 1) m = fmaxf(m, __shfl_xor(m, o));
    if ((tid & 63) == 0) red[h][tid >> 6] = m;
  }
  __syncthreads();
  if (tid < 3) sstat[tid * 2] = fmaxf(fmaxf(red[tid][0], red[tid][1]),
                                      fmaxf(red[tid][2], red[tid][3]));
  __syncthreads();
  // pass 2: per-head sum of exp
#pragma unroll
  for (int h = 0; h < 3; ++h) {
    const float* e_h = e_arr + h * S;
    float mm = sstat[h * 2];
    float ss = 0.f;
    for (int s = tid; s < len; s += 256) ss += __expf(e_h[s] - mm);
#pragma unroll
    for (int o = 32; o >= 1; o >>= 1) ss += __shfl_xor(ss, o);
    if ((tid & 63) == 0) red[h][tid >> 6] = ss;
  }
  __syncthreads();
  if (tid < 3) sstat[tid * 2 + 1] = red[tid][0] + red[tid][1] + red[tid][2] + red[tid][3];
  __syncthreads();

  // fused weights for this block's rows (computed once, not per-thread)
  if (tid < 16 && r0 + tid < len) {
    int r = r0 + tid;
    wrow[tid] = (__expf(e_arr[r] - sstat[0]) / sstat[1] +
                 __expf(e_arr[S + r] - sstat[2]) / sstat[3] +
                 __expf(e_arr[2 * S + r] - sstat[4]) / sstat[5]) * (1.f / 3.f);
  }
  __syncthreads();

  int col = tid * 4;
  int rend = min(r0 + 16, len);
  float4 acc = {0.f, 0.f, 0.f, 0.f};
  for (int r = r0; r < rend; ++r) {
    float w = wrow[r - r0];
    float4 x = *(const float4*)(sent + (size_t)r * H + col);
    acc.x = fmaf(w, x.x, acc.x);
    acc.y = fmaf(w, x.y, acc.y);
    acc.z = fmaf(w, x.z, acc.z);
    acc.w = fmaf(w, x.w, acc.w);
  }
  atomicAdd(&out[col + 0], acc.x);
  atomicAdd(&out[col + 1], acc.y);
  atomicAdd(&out[col + 2], acc.z);
  atomicAdd(&out[col + 3], acc.w);
}

}  // namespace

extern "C" void kernel_launch(void* const* d_in, const int* in_sizes, int n_in,
                              void* d_out, int out_size, void* d_ws, size_t ws_size,
                              hipStream_t stream) {
  const float* sentence = (const float*)d_in[0];
  const int* length     = (const int*)d_in[1];
  const float* ctx_p = (const float*)d_in[2];
  const float* ctx_c = (const float*)d_in[3];
  const float* ctx_h = (const float*)d_in[4];
  const float* W_s[3] = {(const float*)d_in[5],  (const float*)d_in[11], (const float*)d_in[17]};
  const float* b_s[3] = {(const float*)d_in[6],  (const float*)d_in[12], (const float*)d_in[18]};
  const float* W_c[3] = {(const float*)d_in[7],  (const float*)d_in[13], (const float*)d_in[19]};
  const float* b_c[3] = {(const float*)d_in[8],  (const float*)d_in[14], (const float*)d_in[20]};
  const float* v_[3]  = {(const float*)d_in[9],  (const float*)d_in[15], (const float*)d_in[21]};
  float* out = (float*)d_out;

  // workspace layout (bytes)
  char* ws = (char*)d_ws;
  __bf16* sentB = (__bf16*)(ws);               // 8192*1024*2   = 16777216
  __bf16* WtB   = (__bf16*)(ws + 16777216);    // 3*2048*1024*2 = 12582912
  float* e_arr  = (float*)(ws + 29384704);     // 3*8192*4      = 98304

  // 3 graph nodes, no memsets: e_arr/out zeroed inside k_prep, ctxb computed inside k_gemm_e.
  k_prep<<<5640, 256, 0, stream>>>(sentence, sentB,
                                   W_s[0], W_s[1], W_s[2], WtB,
                                   e_arr, length, out, out_size);
  k_gemm_e<<<dim3(S / 64, A / 128, 3), 256, 0, stream>>>(
      sentB, WtB,
      ctx_p, ctx_c, ctx_h,
      W_c[0], W_c[1], W_c[2],
      b_s[0], b_s[1], b_s[2],
      b_c[0], b_c[1], b_c[2],
      v_[0], v_[1], v_[2], length, e_arr);
  k_out<<<S / 16, 256, 0, stream>>>(sentence, e_arr, length, out);
}

// Round 5
// 230.282 us; speedup vs baseline: 1.2122x; 1.0919x over previous
//
#include <hip/hip_runtime.h>
#include <hip/hip_bf16.h>
#include <stdint.h>

// Problem: 3x Bahdanau attention (p/c/h heads) -> averaged softmax weights -> weighted sum of sentence.
// S=8192, H2=1024, A=2048, E=768. All inputs fp32; output fp32 [1024].
// R4: 212.8us total, gemm 54.2us (64x128, 3 bufs, vmcnt(3)) -- best.
// R5: 279us. 128^2 tile: TLP halved -> 84.6us gemm. 24-block ctxb: +45us prep.
// R6: 251us. ctxb-in-prologue poisoned the pipeline (Wc loads share vmcnt -> compiler drain;
//     +77MB redundant fetch); gemm 110us despite depth-3.
// Ledger: total ~= sum(kernels) + ~100us constant (verified across R2-R6 deltas).
// R7: (a) BM=BN=64: 2880 live blocks (~4/CU, LDS 32.5KB), wave tile 32x32 -> 512B LDS/MFMA;
//     (b) clean depth-3 (4 bufs, vmcnt(4), peeled tail), no foreign vmem ops in the loop;
//     (c) ctxb = 96-block quarter-partials, direct store; epilogue sums 4 L2-hot values.
//     3 graph nodes, no memset, no atomics on ctxb.

namespace {

constexpr int S = 8192;
constexpr int H = 1024;   // H2
constexpr int A = 2048;
constexpr int E = 768;

typedef __bf16 bf16x8 __attribute__((ext_vector_type(8)));
typedef float f32x4 __attribute__((ext_vector_type(4)));

__device__ __forceinline__ void gl_lds16(const void* g, void* l) {
  __builtin_amdgcn_global_load_lds(
      (const __attribute__((address_space(1))) void*)g,
      (__attribute__((address_space(3))) void*)l, 16, 0, 0);
}

// ---------- merged prep ----------
// [0,4096)      cvt sentence->bf16 (only rows < round_up(len,64))
// [4096,5632)   transpose W_sent fp32 [H][A] -> bf16 [A][H]
// [5632,5728)   ctxb_q[q][head][a] = partial ctx @ W_ctx over e-quarter q (+biases in q0)
// [5728,5736)   zero e_arr + out
__global__ __launch_bounds__(256)
void k_prep(const float* __restrict__ sentence, __bf16* __restrict__ sentB,
            const float* __restrict__ Wp, const float* __restrict__ Wc_s,
            const float* __restrict__ Wh, __bf16* __restrict__ WtB,
            const float* __restrict__ ctx_p, const float* __restrict__ ctx_c,
            const float* __restrict__ ctx_h,
            const float* __restrict__ Wcx_p, const float* __restrict__ Wcx_c,
            const float* __restrict__ Wcx_h,
            const float* __restrict__ bs_p, const float* __restrict__ bs_c,
            const float* __restrict__ bs_h,
            const float* __restrict__ bc_p, const float* __restrict__ bc_c,
            const float* __restrict__ bc_h,
            float* __restrict__ ctxb_q, float* __restrict__ e_arr,
            const int* __restrict__ length, float* __restrict__ out, int n_out) {
  __shared__ float tile[64][65];
  int b = blockIdx.x;
  int t = threadIdx.x;

  if (b < 4096) {
    // ---- phase 1: sentence fp32 -> bf16, 8 elems/thread; 2 rows per block ----
    int len = min(max(length[0], 0), S);
    int lenp = (len + 63) & ~63;          // GEMM touches rows < round_up(len,64)
    if (b * 2 >= lenp) return;
    int g = b * 256 + t;
    const float4* s4 = (const float4*)sentence + (size_t)g * 2;
    float4 a = s4[0], c = s4[1];
    bf16x8 o;
    o[0] = (__bf16)a.x; o[1] = (__bf16)a.y; o[2] = (__bf16)a.z; o[3] = (__bf16)a.w;
    o[4] = (__bf16)c.x; o[5] = (__bf16)c.y; o[6] = (__bf16)c.z; o[7] = (__bf16)c.w;
    *((bf16x8*)sentB + g) = o;
  } else if (b < 5632) {
    // ---- phase 2: W_sent [H][A] fp32 -> Wt [A][H] bf16 ----
    int r = b - 4096;                 // 512 tiles per head
    int head = r >> 9; r &= 511;
    const float* W = head == 0 ? Wp : (head == 1 ? Wc_s : Wh);
    __bf16* dst = WtB + (size_t)head * A * H;
    int a0 = (r & 31) * 64;           // 32 a-tiles
    int k0 = (r >> 5) * 64;           // 16 k-tiles
#pragma unroll
    for (int i = 0; i < 16; ++i) {
      int idx = t + i * 256;
      int rr = idx >> 6, cc = idx & 63;
      tile[cc][rr] = W[(size_t)(k0 + rr) * A + a0 + cc];   // coalesced over cc
    }
    __syncthreads();
#pragma unroll
    for (int i = 0; i < 16; ++i) {
      int idx = t + i * 256;
      int al = idx >> 6, kl = idx & 63;
      dst[(size_t)(a0 + al) * H + k0 + kl] = (__bf16)tile[al][kl];  // coalesced over kl
    }
  } else if (b < 5728) {
    // ---- phase 3: ctxb quarter-partials, direct store (no atomics -> no memset) ----
    int r = b - 5632;                 // 96 blocks: 3 heads x {8 a-blocks x 4 e-quarters}
    int head = r >> 5;
    int sub = r & 31;
    int ablk = sub & 7;
    int eq = sub >> 3;                // e-quarter: 192 elements
    const float* ctx = head == 0 ? ctx_p : (head == 1 ? ctx_c : ctx_h);
    const float* Wc  = head == 0 ? Wcx_p : (head == 1 ? Wcx_c : Wcx_h);
    int a = ablk * 256 + t;
    float s = 0.f;
    if (eq == 0) {
      const float* bs = head == 0 ? bs_p : (head == 1 ? bs_c : bs_h);
      const float* bc = head == 0 ? bc_p : (head == 1 ? bc_c : bc_h);
      s = bs[a] + bc[a];
    }
    int e0 = eq * 192;
#pragma unroll 8
    for (int e = e0; e < e0 + 192; ++e) s = fmaf(ctx[e], Wc[(size_t)e * A + a], s);
    ctxb_q[eq * 3 * A + head * A + a] = s;
  } else {
    // ---- phase 4: zero e_arr (6144 float4) + out ----
    int idx = (b - 5728) * 256 + t;   // 8 blocks x 256 threads = 2048 strides
    float4 z = {0.f, 0.f, 0.f, 0.f};
    int total = 6144 + (n_out >> 2);
    for (int i = idx; i < total; i += 2048) {
      if (i < 6144) ((float4*)e_arr)[i] = z;
      else ((float4*)out)[i - 6144] = z;
    }
  }
}

// ---------- GEMM + fused tanh*v epilogue -> e[head][s] ----------
// 64x64 tile, BK=32, 4 waves (wave tile 32x32), 4 LDS bufs, depth-3, counted vmcnt(4)
// (2 gl_lds16 per stage per wave). Raw s_barrier + clobber-free waitcnt + sched_barrier(0)
// (R3 lesson: "memory" clobber => vmcnt(0) drain; R6 lesson: no foreign vmem ops in loop).
__global__ __launch_bounds__(256)
void k_gemm_e(const __bf16* __restrict__ sentB, const __bf16* __restrict__ WtB,
              const float* __restrict__ ctxb_q,
              const float* __restrict__ v_p, const float* __restrict__ v_c,
              const float* __restrict__ v_h,
              const int* __restrict__ length, float* __restrict__ e_out) {
  int m0 = blockIdx.x * 64;
  int len = min(max(length[0], 0), S);
  if (m0 >= len) return;          // masked rows can never influence the softmax
  int n0 = blockIdx.y * 64;
  int head = blockIdx.z;
  const float* v  = head == 0 ? v_p : (head == 1 ? v_c : v_h);
  const __bf16* Wt = WtB + (size_t)head * A * H;
  float* e_h = e_out + head * S;

  __shared__ __align__(16) __bf16 lsA[4 * 2048];   // 4 bufs x [64 rows][32 k] = 16 KB
  __shared__ __align__(16) __bf16 lsB[4 * 2048];   // 16 KB
  __shared__ float e_part[64];

  int tid = threadIdx.x;
  if (tid < 64) e_part[tid] = 0.f;   // 32 barriers before the epilogue reads it

  int lane = tid & 63;
  int wave = tid >> 6;
  int wm = wave >> 1, wn = wave & 1;       // wave tile: 32 rows x 32 cols
  int quad = lane >> 4, l16 = lane & 15;

  f32x4 acc[2][2];
#pragma unroll
  for (int i = 0; i < 2; ++i)
#pragma unroll
    for (int j = 0; j < 2; ++j) acc[i][j] = (f32x4){0.f, 0.f, 0.f, 0.f};

  const __bf16* gA0 = sentB + (size_t)(m0 + (tid >> 2)) * H + ((tid & 3) * 8);
  const __bf16* gB0 = Wt + (size_t)(n0 + (tid >> 2)) * H + ((tid & 3) * 8);

  // 2 vector-mem instructions per STAGE per wave -> steady-state wait vmcnt(4) with 3 tiles
  // in flight means "oldest tile landed".
#define STAGE(bufi, kk)                                           \
  do {                                                            \
    gl_lds16(gA0 + (kk), lsA + (bufi) * 2048 + tid * 8);          \
    gl_lds16(gB0 + (kk), lsB + (bufi) * 2048 + tid * 8);          \
  } while (0)

#define COMPUTE(bufi)                                                                          \
  do {                                                                                         \
    bf16x8 af[2], bfv[2];                                                                      \
    _Pragma("unroll")                                                                          \
    for (int i = 0; i < 2; ++i)                                                                \
      af[i] = *(const bf16x8*)&lsA[(bufi) * 2048 + (wm * 32 + i * 16 + l16) * 32 + quad * 8];  \
    _Pragma("unroll")                                                                          \
    for (int j = 0; j < 2; ++j)                                                                \
      bfv[j] = *(const bf16x8*)&lsB[(bufi) * 2048 + (wn * 32 + j * 16 + l16) * 32 + quad * 8]; \
    _Pragma("unroll")                                                                          \
    for (int i = 0; i < 2; ++i)                                                                \
      _Pragma("unroll")                                                                        \
      for (int j = 0; j < 2; ++j)                                                              \
        acc[i][j] = __builtin_amdgcn_mfma_f32_16x16x32_bf16(af[i], bfv[j], acc[i][j], 0, 0, 0);\
  } while (0)

  // prologue: 3 tiles in flight (6 loads)
  STAGE(0, 0);
  STAGE(1, 32);
  STAGE(2, 64);
#pragma unroll 1
  for (int t = 0; t < 29; ++t) {
    asm volatile("s_waitcnt vmcnt(4)");        // tile t landed; t+1,t+2 stay in flight
    __builtin_amdgcn_s_barrier();              // all waves' tile-t writes visible
    __builtin_amdgcn_sched_barrier(0);         // no ds_read hoists above this point
    STAGE((t + 3) & 3, (t + 3) * 32);          // overwrites buf of tile t-1 (barrier-protected)
    COMPUTE(t & 3);
  }
  // peeled tail with exact counts: tile 29 (4 left), 30 (2 left), 31 (0 left)
  asm volatile("s_waitcnt vmcnt(4)");
  __builtin_amdgcn_s_barrier();
  __builtin_amdgcn_sched_barrier(0);
  COMPUTE(1);
  asm volatile("s_waitcnt vmcnt(2)");
  __builtin_amdgcn_s_barrier();
  __builtin_amdgcn_sched_barrier(0);
  COMPUTE(2);
  asm volatile("s_waitcnt vmcnt(0)");
  __builtin_amdgcn_s_barrier();
  __builtin_amdgcn_sched_barrier(0);
  COMPUTE(3);

#undef STAGE
#undef COMPUTE

  float vj[2], cbj[2];
#pragma unroll
  for (int j = 0; j < 2; ++j) {
    int col = n0 + wn * 32 + j * 16 + l16;
    vj[j] = v[col];
    // sum the 4 e-quarter partials (L2-hot, 98KB table)
    cbj[j] = ctxb_q[head * A + col] + ctxb_q[3 * A + head * A + col] +
             ctxb_q[6 * A + head * A + col] + ctxb_q[9 * A + head * A + col];
  }
#pragma unroll
  for (int i = 0; i < 2; ++i) {
#pragma unroll
    for (int r = 0; r < 4; ++r) {
      float p = 0.f;
#pragma unroll
      for (int j = 0; j < 2; ++j) {
        float u = acc[i][j][r] + cbj[j];
        float ex = __expf(2.f * u);        // tanh = 1 - 2/(e^2x+1); inf-safe at both ends
        float th = 1.f - 2.f / (ex + 1.f);
        p = fmaf(th, vj[j], p);
      }
      p += __shfl_xor(p, 1);
      p += __shfl_xor(p, 2);
      p += __shfl_xor(p, 4);
      p += __shfl_xor(p, 8);
      if (l16 == 0) atomicAdd(&e_part[wm * 32 + i * 16 + quad * 4 + r], p);
    }
  }
  __syncthreads();
  if (tid < 64) atomicAdd(&e_h[m0 + tid], e_part[tid]);
}

// ---------- out[h] = sum_s w(s) * sentence[s][h]; softmax stats computed per block ----------
// Stats are redundant per block (e_arr is L2-resident) but remove a dispatch + edge.
__global__ void k_out(const float* __restrict__ sent, const float* __restrict__ e_arr,
                      const int* __restrict__ length, float* __restrict__ out) {
  int len = min(max(length[0], 0), S);
  int r0 = blockIdx.x * 16;
  if (r0 >= len) return;
  int tid = threadIdx.x;

  __shared__ float red[3][4];
  __shared__ float sstat[6];    // m0,s0,m1,s1,m2,s2
  __shared__ float wrow[16];

  // pass 1: per-head max over s < len
#pragma unroll
  for (int h = 0; h < 3; ++h) {
    const float* e_h = e_arr + h * S;
    float m = -3.4e38f;
    for (int s = tid; s < len; s += 256) m = fmaxf(m, e_h[s]);
#pragma unroll
    for (int o = 32; o >= 1; o >>= 1) m = fmaxf(m, __shfl_xor(m, o));
    if ((tid & 63) == 0) red[h][tid >> 6] = m;
  }
  __syncthreads();
  if (tid < 3) sstat[tid * 2] = fmaxf(fmaxf(red[tid][0], red[tid][1]),
                                      fmaxf(red[tid][2], red[tid][3]));
  __syncthreads();
  // pass 2: per-head sum of exp
#pragma unroll
  for (int h = 0; h < 3; ++h) {
    const float* e_h = e_arr + h * S;
    float mm = sstat[h * 2];
    float ss = 0.f;
    for (int s = tid; s < len; s += 256) ss += __expf(e_h[s] - mm);
#pragma unroll
    for (int o = 32; o >= 1; o >>= 1) ss += __shfl_xor(ss, o);
    if ((tid & 63) == 0) red[h][tid >> 6] = ss;
  }
  __syncthreads();
  if (tid < 3) sstat[tid * 2 + 1] = red[tid][0] + red[tid][1] + red[tid][2] + red[tid][3];
  __syncthreads();

  // fused weights for this block's rows (computed once, not per-thread)
  if (tid < 16 && r0 + tid < len) {
    int r = r0 + tid;
    wrow[tid] = (__expf(e_arr[r] - sstat[0]) / sstat[1] +
                 __expf(e_arr[S + r] - sstat[2]) / sstat[3] +
                 __expf(e_arr[2 * S + r] - sstat[4]) / sstat[5]) * (1.f / 3.f);
  }
  __syncthreads();

  int col = tid * 4;
  int rend = min(r0 + 16, len);
  float4 acc = {0.f, 0.f, 0.f, 0.f};
  for (int r = r0; r < rend; ++r) {
    float w = wrow[r - r0];
    float4 x = *(const float4*)(sent + (size_t)r * H + col);
    acc.x = fmaf(w, x.x, acc.x);
    acc.y = fmaf(w, x.y, acc.y);
    acc.z = fmaf(w, x.z, acc.z);
    acc.w = fmaf(w, x.w, acc.w);
  }
  atomicAdd(&out[col + 0], acc.x);
  atomicAdd(&out[col + 1], acc.y);
  atomicAdd(&out[col + 2], acc.z);
  atomicAdd(&out[col + 3], acc.w);
}

}  // namespace

extern "C" void kernel_launch(void* const* d_in, const int* in_sizes, int n_in,
                              void* d_out, int out_size, void* d_ws, size_t ws_size,
                              hipStream_t stream) {
  const float* sentence = (const float*)d_in[0];
  const int* length     = (const int*)d_in[1];
  const float* ctx_p = (const float*)d_in[2];
  const float* ctx_c = (const float*)d_in[3];
  const float* ctx_h = (const float*)d_in[4];
  const float* W_s[3] = {(const float*)d_in[5],  (const float*)d_in[11], (const float*)d_in[17]};
  const float* b_s[3] = {(const float*)d_in[6],  (const float*)d_in[12], (const float*)d_in[18]};
  const float* W_c[3] = {(const float*)d_in[7],  (const float*)d_in[13], (const float*)d_in[19]};
  const float* b_c[3] = {(const float*)d_in[8],  (const float*)d_in[14], (const float*)d_in[20]};
  const float* v_[3]  = {(const float*)d_in[9],  (const float*)d_in[15], (const float*)d_in[21]};
  float* out = (float*)d_out;

  // workspace layout (bytes)
  char* ws = (char*)d_ws;
  __bf16* sentB  = (__bf16*)(ws);               // 8192*1024*2   = 16777216
  __bf16* WtB    = (__bf16*)(ws + 16777216);    // 3*2048*1024*2 = 12582912
  float* ctxb_q  = (float*)(ws + 29360128);     // 4*3*2048*4    = 98304
  float* e_arr   = (float*)(ws + 29458432);     // 3*8192*4      = 98304

  // 3 graph nodes, no memsets, no cross-kernel atomics except e_arr/out (zeroed in prep).
  k_prep<<<5736, 256, 0, stream>>>(sentence, sentB,
                                   W_s[0], W_s[1], W_s[2], WtB,
                                   ctx_p, ctx_c, ctx_h,
                                   W_c[0], W_c[1], W_c[2],
                                   b_s[0], b_s[1], b_s[2],
                                   b_c[0], b_c[1], b_c[2], ctxb_q, e_arr,
                                   length, out, out_size);
  k_gemm_e<<<dim3(S / 64, A / 64, 3), 256, 0, stream>>>(sentB, WtB, ctxb_q,
                                                        v_[0], v_[1], v_[2], length, e_arr);
  k_out<<<S / 16, 256, 0, stream>>>(sentence, e_arr, length, out);
}

// Round 6
// 213.505 us; speedup vs baseline: 1.3075x; 1.0786x over previous
//
#include <hip/hip_runtime.h>
#include <hip/hip_bf16.h>
#include <stdint.h>

// Problem: 3x Bahdanau attention (p/c/h heads) -> averaged softmax weights -> weighted sum of sentence.
// S=8192, H2=1024, A=2048, E=768. All inputs fp32; output fp32 [1024].
// R4: 212.8us total, gemm 54.2us (64x128, 3 bufs, depth-2, vmcnt(3), 4 blk/CU) -- proven best shape.
// R5/R6/R7 regressions: 128^2 (TLP), ctxb-in-prologue (vmcnt poison), BN=64 (1KB LDS-read/MFMA,
//     conflicts 5.7M). Ranking across R4-R7 tracks (LDS bytes/MFMA) x TLP -> R4 optimal.
// R8: ONE change on the R4 gemm: XCD panel-local block mapping. xcd=bid&7 owns 6 of 48 (n,head)
//     panels (1.5MB B resident in its L2 for the whole kernel); m is OUTER within an XCD so the
//     6 concurrent panel-blocks share each A m-tile. Stage loads: L3(~600cy) -> L2(~200cy), which
//     depth-2's ~300cy cover can actually hide. Also: phase-2 transpose widened (float2/ushort2),
//     k_stats un-fused (3 blocks) so k_out drops its redundant stats passes.

namespace {

constexpr int S = 8192;
constexpr int H = 1024;   // H2
constexpr int A = 2048;
constexpr int E = 768;

typedef __bf16 bf16x8 __attribute__((ext_vector_type(8)));
typedef float f32x4 __attribute__((ext_vector_type(4)));

__device__ __forceinline__ void gl_lds16(const void* g, void* l) {
  __builtin_amdgcn_global_load_lds(
      (const __attribute__((address_space(1))) void*)g,
      (__attribute__((address_space(3))) void*)l, 16, 0, 0);
}

// ---------- merged prep ----------
// [0,4096)      cvt sentence->bf16 (only rows < round_up(len,64))
// [4096,5632)   transpose W_sent fp32 [H][A] -> bf16 [A][H]  (float2 in / ushort2 out)
// [5632,5728)   ctxb_q[q][head][a] = partial ctx @ W_ctx over e-quarter q (+biases in q0)
// [5728,5736)   zero e_arr + out
__global__ __launch_bounds__(256)
void k_prep(const float* __restrict__ sentence, __bf16* __restrict__ sentB,
            const float* __restrict__ Wp, const float* __restrict__ Wc_s,
            const float* __restrict__ Wh, __bf16* __restrict__ WtB,
            const float* __restrict__ ctx_p, const float* __restrict__ ctx_c,
            const float* __restrict__ ctx_h,
            const float* __restrict__ Wcx_p, const float* __restrict__ Wcx_c,
            const float* __restrict__ Wcx_h,
            const float* __restrict__ bs_p, const float* __restrict__ bs_c,
            const float* __restrict__ bs_h,
            const float* __restrict__ bc_p, const float* __restrict__ bc_c,
            const float* __restrict__ bc_h,
            float* __restrict__ ctxb_q, float* __restrict__ e_arr,
            const int* __restrict__ length, float* __restrict__ out, int n_out) {
  __shared__ float tile[64][65];
  int b = blockIdx.x;
  int t = threadIdx.x;

  if (b < 4096) {
    // ---- phase 1: sentence fp32 -> bf16, 8 elems/thread; 2 rows per block ----
    int len = min(max(length[0], 0), S);
    int lenp = (len + 63) & ~63;          // GEMM touches rows < round_up(len,64)
    if (b * 2 >= lenp) return;
    int g = b * 256 + t;
    const float4* s4 = (const float4*)sentence + (size_t)g * 2;
    float4 a = s4[0], c = s4[1];
    bf16x8 o;
    o[0] = (__bf16)a.x; o[1] = (__bf16)a.y; o[2] = (__bf16)a.z; o[3] = (__bf16)a.w;
    o[4] = (__bf16)c.x; o[5] = (__bf16)c.y; o[6] = (__bf16)c.z; o[7] = (__bf16)c.w;
    *((bf16x8*)sentB + g) = o;
  } else if (b < 5632) {
    // ---- phase 2: W_sent [H][A] fp32 -> Wt [A][H] bf16, widened both sides ----
    int r = b - 4096;                 // 512 tiles per head
    int head = r >> 9; r &= 511;
    const float* W = head == 0 ? Wp : (head == 1 ? Wc_s : Wh);
    __bf16* dst = WtB + (size_t)head * A * H;
    int a0 = (r & 31) * 64;           // 32 a-tiles
    int k0 = (r >> 5) * 64;           // 16 k-tiles
#pragma unroll
    for (int i = 0; i < 8; ++i) {
      int idx = t + i * 256;
      int rr = idx >> 5;              // k-row 0..63
      int cc = (idx & 31) * 2;        // a-col pairs: float2 loads, 2-way LDS banks (free)
      float2 w2 = *(const float2*)&W[(size_t)(k0 + rr) * A + a0 + cc];
      tile[cc][rr] = w2.x;
      tile[cc + 1][rr] = w2.y;
    }
    __syncthreads();
#pragma unroll
    for (int i = 0; i < 8; ++i) {
      int idx = t + i * 256;
      int al = idx >> 5;              // a-row
      int kl = (idx & 31) * 2;        // k pair: ushort2 store, 256B/wave-segment
      union { ushort2 u; __bf16 h[2]; } o;
      o.h[0] = (__bf16)tile[al][kl];
      o.h[1] = (__bf16)tile[al][kl + 1];
      *(ushort2*)&dst[(size_t)(a0 + al) * H + k0 + kl] = o.u;
    }
  } else if (b < 5728) {
    // ---- phase 3: ctxb quarter-partials, direct store (no atomics -> no memset) ----
    int r = b - 5632;                 // 96 blocks: 3 heads x {8 a-blocks x 4 e-quarters}
    int head = r >> 5;
    int sub = r & 31;
    int ablk = sub & 7;
    int eq = sub >> 3;                // e-quarter: 192 elements
    const float* ctx = head == 0 ? ctx_p : (head == 1 ? ctx_c : ctx_h);
    const float* Wc  = head == 0 ? Wcx_p : (head == 1 ? Wcx_c : Wcx_h);
    int a = ablk * 256 + t;
    float s = 0.f;
    if (eq == 0) {
      const float* bs = head == 0 ? bs_p : (head == 1 ? bs_c : bs_h);
      const float* bc = head == 0 ? bc_p : (head == 1 ? bc_c : bc_h);
      s = bs[a] + bc[a];
    }
    int e0 = eq * 192;
#pragma unroll 8
    for (int e = e0; e < e0 + 192; ++e) s = fmaf(ctx[e], Wc[(size_t)e * A + a], s);
    ctxb_q[eq * 3 * A + head * A + a] = s;
  } else {
    // ---- phase 4: zero e_arr (6144 float4) + out ----
    int idx = (b - 5728) * 256 + t;   // 8 blocks x 256 threads = 2048 strides
    float4 z = {0.f, 0.f, 0.f, 0.f};
    int total = 6144 + (n_out >> 2);
    for (int i = idx; i < total; i += 2048) {
      if (i < 6144) ((float4*)e_arr)[i] = z;
      else ((float4*)out)[i - 6144] = z;
    }
  }
}

// ---------- GEMM + fused tanh*v epilogue -> e[head][s] ----------
// EXACT R4 inner structure (64x128 tile, BK=32, 3 bufs, depth-2, counted vmcnt(3), raw
// s_barrier + clobber-free waitcnt + sched_barrier(0)). New: XCD panel-local mapping --
// xcd=bid&7 owns panels [xcd*6, xcd*6+6) of 48 (n,head) panels; within an XCD, m is the
// OUTER coordinate so the 6 concurrent panel-blocks share each A tile and the 1.5MB B set
// stays resident in that XCD's L2. (Round-robin bid->XCD is a heuristic: if the mapping
// differs, this degrades to the old random placement, not worse.)
__global__ __launch_bounds__(256)
void k_gemm_e(const __bf16* __restrict__ sentB, const __bf16* __restrict__ WtB,
              const float* __restrict__ ctxb_q,
              const float* __restrict__ v_p, const float* __restrict__ v_c,
              const float* __restrict__ v_h,
              const int* __restrict__ length, float* __restrict__ e_out) {
  int bid = blockIdx.x;
  int xcd = bid & 7;
  int j = bid >> 3;                  // [0, 768)
  int mt = j / 6;                    // m OUTER within XCD: 128 m-tiles
  int pl = j - mt * 6;               // 6 panels per XCD
  int panel = xcd * 6 + pl;          // [0, 48)
  int n0 = (panel & 15) * 128;
  int head = panel >> 4;

  int m0 = mt * 64;
  int len = min(max(length[0], 0), S);
  if (m0 >= len) return;          // masked rows can never influence the softmax
  const float* v  = head == 0 ? v_p : (head == 1 ? v_c : v_h);
  const __bf16* Wt = WtB + (size_t)head * A * H;
  float* e_h = e_out + head * S;

  __shared__ __align__(16) __bf16 lsA[3 * 2048];   // 3 bufs x [64 rows][32 k]
  __shared__ __align__(16) __bf16 lsB[3 * 4096];   // 3 bufs x [128 rows][32 k]
  __shared__ float e_part[64];

  int tid = threadIdx.x;
  if (tid < 64) e_part[tid] = 0.f;   // 32 barriers before the epilogue reads it

  int lane = tid & 63;
  int wave = tid >> 6;
  int wm = wave >> 1, wn = wave & 1;       // wave tile: 32 rows x 64 cols
  int quad = lane >> 4, l16 = lane & 15;

  f32x4 acc[2][4];
#pragma unroll
  for (int i = 0; i < 2; ++i)
#pragma unroll
    for (int j2 = 0; j2 < 4; ++j2) acc[i][j2] = (f32x4){0.f, 0.f, 0.f, 0.f};

  const __bf16* gA0 = sentB + (size_t)(m0 + (tid >> 2)) * H + ((tid & 3) * 8);
  const __bf16* gB0 = Wt + (size_t)(n0 + (tid >> 2)) * H + ((tid & 3) * 8);
  const __bf16* gB1 = gB0 + (size_t)64 * H;

  // 3 vector-mem instructions per STAGE -> vmcnt(3) == "previous tile's stage complete".
#define STAGE(bufi, kk)                                           \
  do {                                                            \
    gl_lds16(gA0 + (kk), lsA + (bufi) * 2048 + tid * 8);          \
    gl_lds16(gB0 + (kk), lsB + (bufi) * 4096 + tid * 8);          \
    gl_lds16(gB1 + (kk), lsB + (bufi) * 4096 + 2048 + tid * 8);   \
  } while (0)

#define COMPUTE(bufi)                                                                          \
  do {                                                                                         \
    bf16x8 af[2], bfv[4];                                                                      \
    _Pragma("unroll")                                                                          \
    for (int i = 0; i < 2; ++i)                                                                \
      af[i] = *(const bf16x8*)&lsA[(bufi) * 2048 + (wm * 32 + i * 16 + l16) * 32 + quad * 8];  \
    _Pragma("unroll")                                                                          \
    for (int jj = 0; jj < 4; ++jj)                                                             \
      bfv[jj] = *(const bf16x8*)&lsB[(bufi) * 4096 + (wn * 64 + jj * 16 + l16) * 32 + quad * 8]; \
    _Pragma("unroll")                                                                          \
    for (int i = 0; i < 2; ++i)                                                                \
      _Pragma("unroll")                                                                        \
      for (int jj = 0; jj < 4; ++jj)                                                           \
        acc[i][jj] = __builtin_amdgcn_mfma_f32_16x16x32_bf16(af[i], bfv[jj], acc[i][jj], 0, 0, 0);\
  } while (0)

  // prologue: 2 tiles in flight
  STAGE(0, 0);
  STAGE(1, 32);
  int cur = 0, pf = 2;
#pragma unroll 1
  for (int t = 0; t < 31; ++t) {
    asm volatile("s_waitcnt vmcnt(3)");        // tile t landed (tile t+1's 3 stay in flight)
    __builtin_amdgcn_s_barrier();              // all waves' tile-t writes visible
    __builtin_amdgcn_sched_barrier(0);         // no ds_read hoists above this point
    if (t < 30) STAGE(pf, (t + 2) * 32);       // after barrier: WAR on buffer pf is safe
    COMPUTE(cur);
    cur = cur == 2 ? 0 : cur + 1;
    pf = pf == 2 ? 0 : pf + 1;
  }
  asm volatile("s_waitcnt vmcnt(0)");
  __builtin_amdgcn_s_barrier();
  __builtin_amdgcn_sched_barrier(0);
  COMPUTE(cur);   // tile 31

#undef STAGE
#undef COMPUTE

  float vj[4], cbj[4];
#pragma unroll
  for (int j2 = 0; j2 < 4; ++j2) {
    int col = n0 + wn * 64 + j2 * 16 + l16;
    vj[j2] = v[col];
    // sum the 4 e-quarter partials (L2-hot, 98KB table); biases folded into quarter 0
    cbj[j2] = ctxb_q[head * A + col] + ctxb_q[3 * A + head * A + col] +
              ctxb_q[6 * A + head * A + col] + ctxb_q[9 * A + head * A + col];
  }
#pragma unroll
  for (int i = 0; i < 2; ++i) {
#pragma unroll
    for (int r = 0; r < 4; ++r) {
      float p = 0.f;
#pragma unroll
      for (int j2 = 0; j2 < 4; ++j2) {
        float u = acc[i][j2][r] + cbj[j2];
        float ex = __expf(2.f * u);        // tanh = 1 - 2/(e^2x+1); inf-safe at both ends
        float th = 1.f - 2.f / (ex + 1.f);
        p = fmaf(th, vj[j2], p);
      }
      p += __shfl_xor(p, 1);
      p += __shfl_xor(p, 2);
      p += __shfl_xor(p, 4);
      p += __shfl_xor(p, 8);
      if (l16 == 0) atomicAdd(&e_part[wm * 32 + i * 16 + quad * 4 + r], p);
    }
  }
  __syncthreads();
  if (tid < 64) atomicAdd(&e_h[m0 + tid], e_part[tid]);
}

// ---------- softmax stats per head (max, sum) over s < len ----------
__global__ void k_stats(const float* __restrict__ e_arr, const int* __restrict__ length,
                        float* __restrict__ stats) {
  int head = blockIdx.x;
  const float* e_h = e_arr + head * S;
  int len = min(max(length[0], 0), S);
  int tid = threadIdx.x;
  __shared__ float red[4];
  __shared__ float bmax;

  float m = -3.4e38f;
  for (int s = tid; s < len; s += 256) m = fmaxf(m, e_h[s]);
#pragma unroll
  for (int o = 32; o >= 1; o >>= 1) m = fmaxf(m, __shfl_xor(m, o));
  if ((tid & 63) == 0) red[tid >> 6] = m;
  __syncthreads();
  if (tid == 0) bmax = fmaxf(fmaxf(red[0], red[1]), fmaxf(red[2], red[3]));
  __syncthreads();
  float mm = bmax;

  float ss = 0.f;
  for (int s = tid; s < len; s += 256) ss += __expf(e_h[s] - mm);
#pragma unroll
  for (int o = 32; o >= 1; o >>= 1) ss += __shfl_xor(ss, o);
  __syncthreads();
  if ((tid & 63) == 0) red[tid >> 6] = ss;
  __syncthreads();
  if (tid == 0) {
    stats[head * 2 + 0] = mm;
    stats[head * 2 + 1] = red[0] + red[1] + red[2] + red[3];
  }
}

// ---------- out[h] = sum_s w(s) * sentence[s][h], w from e+stats (no redundant stats) ----------
__global__ void k_out(const float* __restrict__ sent, const float* __restrict__ e_arr,
                      const float* __restrict__ stats, const int* __restrict__ length,
                      float* __restrict__ out) {
  int len = min(max(length[0], 0), S);
  int r0 = blockIdx.x * 16;
  if (r0 >= len) return;
  int tid = threadIdx.x;

  __shared__ float wrow[16];
  if (tid < 16 && r0 + tid < len) {
    int r = r0 + tid;
    wrow[tid] = (__expf(e_arr[r] - stats[0]) / stats[1] +
                 __expf(e_arr[S + r] - stats[2]) / stats[3] +
                 __expf(e_arr[2 * S + r] - stats[4]) / stats[5]) * (1.f / 3.f);
  }
  __syncthreads();

  int col = tid * 4;
  int rend = min(r0 + 16, len);
  float4 acc = {0.f, 0.f, 0.f, 0.f};
  for (int r = r0; r < rend; ++r) {
    float w = wrow[r - r0];
    float4 x = *(const float4*)(sent + (size_t)r * H + col);
    acc.x = fmaf(w, x.x, acc.x);
    acc.y = fmaf(w, x.y, acc.y);
    acc.z = fmaf(w, x.z, acc.z);
    acc.w = fmaf(w, x.w, acc.w);
  }
  atomicAdd(&out[col + 0], acc.x);
  atomicAdd(&out[col + 1], acc.y);
  atomicAdd(&out[col + 2], acc.z);
  atomicAdd(&out[col + 3], acc.w);
}

}  // namespace

extern "C" void kernel_launch(void* const* d_in, const int* in_sizes, int n_in,
                              void* d_out, int out_size, void* d_ws, size_t ws_size,
                              hipStream_t stream) {
  const float* sentence = (const float*)d_in[0];
  const int* length     = (const int*)d_in[1];
  const float* ctx_p = (const float*)d_in[2];
  const float* ctx_c = (const float*)d_in[3];
  const float* ctx_h = (const float*)d_in[4];
  const float* W_s[3] = {(const float*)d_in[5],  (const float*)d_in[11], (const float*)d_in[17]};
  const float* b_s[3] = {(const float*)d_in[6],  (const float*)d_in[12], (const float*)d_in[18]};
  const float* W_c[3] = {(const float*)d_in[7],  (const float*)d_in[13], (const float*)d_in[19]};
  const float* b_c[3] = {(const float*)d_in[8],  (const float*)d_in[14], (const float*)d_in[20]};
  const float* v_[3]  = {(const float*)d_in[9],  (const float*)d_in[15], (const float*)d_in[21]};
  float* out = (float*)d_out;

  // workspace layout (bytes)
  char* ws = (char*)d_ws;
  __bf16* sentB  = (__bf16*)(ws);               // 8192*1024*2   = 16777216
  __bf16* WtB    = (__bf16*)(ws + 16777216);    // 3*2048*1024*2 = 12582912
  float* ctxb_q  = (float*)(ws + 29360128);     // 4*3*2048*4    = 98304
  float* e_arr   = (float*)(ws + 29458432);     // 3*8192*4      = 98304
  float* stats   = (float*)(ws + 29556736);     // 6 floats

  // 4 graph nodes, no memsets, no cross-kernel atomics except e_arr/out (zeroed in prep).
  k_prep<<<5736, 256, 0, stream>>>(sentence, sentB,
                                   W_s[0], W_s[1], W_s[2], WtB,
                                   ctx_p, ctx_c, ctx_h,
                                   W_c[0], W_c[1], W_c[2],
                                   b_s[0], b_s[1], b_s[2],
                                   b_c[0], b_c[1], b_c[2], ctxb_q, e_arr,
                                   length, out, out_size);
  k_gemm_e<<<6144, 256, 0, stream>>>(sentB, WtB, ctxb_q,
                                     v_[0], v_[1], v_[2], length, e_arr);
  k_stats<<<3, 256, 0, stream>>>(e_arr, length, stats);
  k_out<<<S / 16, 256, 0, stream>>>(sentence, e_arr, stats, length, out);
}

// Round 8
// 210.493 us; speedup vs baseline: 1.3262x; 1.0143x over previous
//
#include <hip/hip_runtime.h>
#include <hip/hip_bf16.h>
#include <stdint.h>

// Problem: 3x Bahdanau attention (p/c/h heads) -> averaged softmax weights -> weighted sum of sentence.
// S=8192, H2=1024, A=2048, E=768. All inputs fp32; output fp32 [1024].
// R4/R8: gemm 54.2-54.6us (64x128, depth-2 counted vmcnt, XCD panel map). R8's XCD map cut FETCH
//     54.7->21.8MB with ZERO time delta => gemm is NOT memory-bound. SQ_LDS_BANK_CONFLICT 4.28M
//     (~4cyc/ds_read_b128): 64B row pitch -> row-parity 8-way conflict; LDS path ~8x MFMA cycles.
// R5 lesson: swizzle at 64B pitch is a no-op (2 bits). G4 fix = padded pitch, impossible with
//     global_load_lds (linear dest, m173) -> R9 switches staging to global->reg->LDS.
// R9: pitch 40 elems (80B): bank-group (5*row+chunk)%8 -> 64-lane b128 = exactly 2/bank (free,
//     m136). Same formula for ds_write and ds_read => conflict-free both sides. Compiler emits
//     exact vmcnt for reg->LDS (dataflow, no drain); raw s_barrier + lgkmcnt(0) + sched_barrier
//     publishes. 3 load slots (static names, rule #20), 1-iter cover (stages are L2-hot via XCD map).
// R9b: resubmit of R9 -- previous round was a container-level infra failure (no kernel verdict);
//     source re-audited for OOB/deadlock/graph-capture hazards: none found.

namespace {

constexpr int S = 8192;
constexpr int H = 1024;   // H2
constexpr int A = 2048;
constexpr int E = 768;

typedef __bf16 bf16x8 __attribute__((ext_vector_type(8)));
typedef float f32x4 __attribute__((ext_vector_type(4)));

// ---------- merged prep ----------
// [0,4096)      cvt sentence->bf16 (only rows < round_up(len,64))
// [4096,5632)   transpose W_sent fp32 [H][A] -> bf16 [A][H]  (float2 in / ushort2 out)
// [5632,5728)   ctxb_q[q][head][a] = partial ctx @ W_ctx over e-quarter q (+biases in q0)
// [5728,5736)   zero e_arr + out
__global__ __launch_bounds__(256)
void k_prep(const float* __restrict__ sentence, __bf16* __restrict__ sentB,
            const float* __restrict__ Wp, const float* __restrict__ Wc_s,
            const float* __restrict__ Wh, __bf16* __restrict__ WtB,
            const float* __restrict__ ctx_p, const float* __restrict__ ctx_c,
            const float* __restrict__ ctx_h,
            const float* __restrict__ Wcx_p, const float* __restrict__ Wcx_c,
            const float* __restrict__ Wcx_h,
            const float* __restrict__ bs_p, const float* __restrict__ bs_c,
            const float* __restrict__ bs_h,
            const float* __restrict__ bc_p, const float* __restrict__ bc_c,
            const float* __restrict__ bc_h,
            float* __restrict__ ctxb_q, float* __restrict__ e_arr,
            const int* __restrict__ length, float* __restrict__ out, int n_out) {
  __shared__ float tile[64][65];
  int b = blockIdx.x;
  int t = threadIdx.x;

  if (b < 4096) {
    // ---- phase 1: sentence fp32 -> bf16, 8 elems/thread; 2 rows per block ----
    int len = min(max(length[0], 0), S);
    int lenp = (len + 63) & ~63;          // GEMM touches rows < round_up(len,64)
    if (b * 2 >= lenp) return;
    int g = b * 256 + t;
    const float4* s4 = (const float4*)sentence + (size_t)g * 2;
    float4 a = s4[0], c = s4[1];
    bf16x8 o;
    o[0] = (__bf16)a.x; o[1] = (__bf16)a.y; o[2] = (__bf16)a.z; o[3] = (__bf16)a.w;
    o[4] = (__bf16)c.x; o[5] = (__bf16)c.y; o[6] = (__bf16)c.z; o[7] = (__bf16)c.w;
    *((bf16x8*)sentB + g) = o;
  } else if (b < 5632) {
    // ---- phase 2: W_sent [H][A] fp32 -> Wt [A][H] bf16, widened both sides ----
    int r = b - 4096;                 // 512 tiles per head
    int head = r >> 9; r &= 511;
    const float* W = head == 0 ? Wp : (head == 1 ? Wc_s : Wh);
    __bf16* dst = WtB + (size_t)head * A * H;
    int a0 = (r & 31) * 64;           // 32 a-tiles
    int k0 = (r >> 5) * 64;           // 16 k-tiles
#pragma unroll
    for (int i = 0; i < 8; ++i) {
      int idx = t + i * 256;
      int rr = idx >> 5;              // k-row 0..63
      int cc = (idx & 31) * 2;        // a-col pairs: float2 loads, 2-way LDS banks (free)
      float2 w2 = *(const float2*)&W[(size_t)(k0 + rr) * A + a0 + cc];
      tile[cc][rr] = w2.x;
      tile[cc + 1][rr] = w2.y;
    }
    __syncthreads();
#pragma unroll
    for (int i = 0; i < 8; ++i) {
      int idx = t + i * 256;
      int al = idx >> 5;              // a-row
      int kl = (idx & 31) * 2;        // k pair: ushort2 store, 256B/wave-segment
      union { ushort2 u; __bf16 h[2]; } o;
      o.h[0] = (__bf16)tile[al][kl];
      o.h[1] = (__bf16)tile[al][kl + 1];
      *(ushort2*)&dst[(size_t)(a0 + al) * H + k0 + kl] = o.u;
    }
  } else if (b < 5728) {
    // ---- phase 3: ctxb quarter-partials, direct store (no atomics -> no memset) ----
    int r = b - 5632;                 // 96 blocks: 3 heads x {8 a-blocks x 4 e-quarters}
    int head = r >> 5;
    int sub = r & 31;
    int ablk = sub & 7;
    int eq = sub >> 3;                // e-quarter: 192 elements
    const float* ctx = head == 0 ? ctx_p : (head == 1 ? ctx_c : ctx_h);
    const float* Wc  = head == 0 ? Wcx_p : (head == 1 ? Wcx_c : Wcx_h);
    int a = ablk * 256 + t;
    float s = 0.f;
    if (eq == 0) {
      const float* bs = head == 0 ? bs_p : (head == 1 ? bs_c : bs_h);
      const float* bc = head == 0 ? bc_p : (head == 1 ? bc_c : bc_h);
      s = bs[a] + bc[a];
    }
    int e0 = eq * 192;
#pragma unroll 8
    for (int e = e0; e < e0 + 192; ++e) s = fmaf(ctx[e], Wc[(size_t)e * A + a], s);
    ctxb_q[eq * 3 * A + head * A + a] = s;
  } else {
    // ---- phase 4: zero e_arr (6144 float4) + out ----
    int idx = (b - 5728) * 256 + t;   // 8 blocks x 256 threads = 2048 strides
    float4 z = {0.f, 0.f, 0.f, 0.f};
    int total = 6144 + (n_out >> 2);
    for (int i = idx; i < total; i += 2048) {
      if (i < 6144) ((float4*)e_arr)[i] = z;
      else ((float4*)out)[i - 6144] = z;
    }
  }
}

// ---------- GEMM + fused tanh*v epilogue -> e[head][s] ----------
// 64x128 tile, BK=32. Reg-staged LDS with PITCH=40 elems (80B): conflict-free ds_write_b128 +
// ds_read_b128 (bank-group (5*row+chunk)%8 covers all 8 groups; 2 lanes/bank = free). 3 LDS
// bufs + 3 named load slots, tile x -> slot/buf x%3. Per iter: {COMPUTE(t); issue loads(t+3);
// ds_write(t+2) [compiler-exact vmcnt]; lgkmcnt(0); s_barrier}. XCD panel mapping kept from R8
// (FETCH 22MB, stages are XCD-local L2 hits -> 1-iter load cover suffices).
__global__ __launch_bounds__(256)
void k_gemm_e(const __bf16* __restrict__ sentB, const __bf16* __restrict__ WtB,
              const float* __restrict__ ctxb_q,
              const float* __restrict__ v_p, const float* __restrict__ v_c,
              const float* __restrict__ v_h,
              const int* __restrict__ length, float* __restrict__ e_out) {
  int bid = blockIdx.x;
  int xcd = bid & 7;
  int j = bid >> 3;                  // [0, 768)
  int mt = j / 6;                    // m OUTER within XCD: 128 m-tiles
  int pl = j - mt * 6;               // 6 panels per XCD
  int panel = xcd * 6 + pl;          // [0, 48)
  int n0 = (panel & 15) * 128;
  int head = panel >> 4;

  int m0 = mt * 64;
  int len = min(max(length[0], 0), S);
  if (m0 >= len) return;          // masked rows can never influence the softmax
  const float* v  = head == 0 ? v_p : (head == 1 ? v_c : v_h);
  const __bf16* Wt = WtB + (size_t)head * A * H;
  float* e_h = e_out + head * S;

  // pitch 40 elements: A buf 64*40=2560 elems, B buf 128*40=5120 elems, x3 bufs = 46080 B.
  __shared__ __align__(16) __bf16 lsA[3 * 2560];
  __shared__ __align__(16) __bf16 lsB[3 * 5120];
  __shared__ float e_part[64];

  int tid = threadIdx.x;
  if (tid < 64) e_part[tid] = 0.f;   // 30+ barriers before the epilogue reads it

  int lane = tid & 63;
  int wave = tid >> 6;
  int wm = wave >> 1, wn = wave & 1;       // wave tile: 32 rows x 64 cols
  int quad = lane >> 4, l16 = lane & 15;

  f32x4 acc[2][4];
#pragma unroll
  for (int i = 0; i < 2; ++i)
#pragma unroll
    for (int j2 = 0; j2 < 4; ++j2) acc[i][j2] = (f32x4){0.f, 0.f, 0.f, 0.f};

  // global sources (16B per thread per matrix-half, coalesced)
  const __bf16* gA0 = sentB + (size_t)(m0 + (tid >> 2)) * H + ((tid & 3) * 8);
  const __bf16* gB0 = Wt + (size_t)(n0 + (tid >> 2)) * H + ((tid & 3) * 8);
  const __bf16* gB1 = gB0 + (size_t)64 * H;

  // LDS write addresses (padded pitch, conflict-free)
  int wA  = (tid >> 2) * 40 + (tid & 3) * 8;   // A row, chunk
  int wB0 = wA;                                // B rows 0-63
  int wB1 = wA + 64 * 40;                      // B rows 64-127

  uint4 s0A, s0B0, s0B1, s1A, s1B0, s1B1, s2A, s2B0, s2B1;

#define LOADB(sl, kk)                             \
  do {                                            \
    sl##A  = *(const uint4*)(gA0 + (kk));         \
    sl##B0 = *(const uint4*)(gB0 + (kk));         \
    sl##B1 = *(const uint4*)(gB1 + (kk));         \
  } while (0)

#define WRITEB(sl, bufi)                          \
  do {                                            \
    *(uint4*)&lsA[(bufi) * 2560 + wA]  = sl##A;   \
    *(uint4*)&lsB[(bufi) * 5120 + wB0] = sl##B0;  \
    *(uint4*)&lsB[(bufi) * 5120 + wB1] = sl##B1;  \
  } while (0)

#define COMPUTE(bufi)                                                                           \
  do {                                                                                          \
    bf16x8 af[2], bfv[4];                                                                       \
    _Pragma("unroll")                                                                           \
    for (int i = 0; i < 2; ++i)                                                                 \
      af[i] = *(const bf16x8*)&lsA[(bufi) * 2560 + (wm * 32 + i * 16 + l16) * 40 + quad * 8];   \
    _Pragma("unroll")                                                                           \
    for (int jj = 0; jj < 4; ++jj)                                                              \
      bfv[jj] = *(const bf16x8*)&lsB[(bufi) * 5120 + (wn * 64 + jj * 16 + l16) * 40 + quad * 8];\
    _Pragma("unroll")                                                                           \
    for (int i = 0; i < 2; ++i)                                                                 \
      _Pragma("unroll")                                                                         \
      for (int jj = 0; jj < 4; ++jj)                                                            \
        acc[i][jj] = __builtin_amdgcn_mfma_f32_16x16x32_bf16(af[i], bfv[jj], acc[i][jj], 0, 0, 0);\
  } while (0)

  // One iteration: compute tile t from buf t%3; issue loads for tile t+3 into slot t%3
  // (its old contents were written to LDS at iter t-2); write tile t+2 (slot (t+2)%3) to
  // buf (t+2)%3 (its readers finished at iter t-1, barrier-protected). Compiler inserts
  // the exact vmcnt for the writes' data deps. lgkmcnt(0)+s_barrier publishes the writes.
#define ITER(t, sc, bc, sw, bw)                                 \
  do {                                                          \
    COMPUTE(bc);                                                \
    if ((t) <= 28) LOADB(sc, ((t) + 3) * 32);                   \
    WRITEB(sw, bw);                                             \
    asm volatile("s_waitcnt lgkmcnt(0)");                       \
    __builtin_amdgcn_sched_barrier(0);                          \
    __builtin_amdgcn_s_barrier();                               \
    __builtin_amdgcn_sched_barrier(0);                          \
  } while (0)

  // prologue: tiles 0,1,2 in regs; 0,1 into LDS (compiler vmcnt-waits s0/s1 exactly)
  LOADB(s0, 0);
  LOADB(s1, 32);
  LOADB(s2, 64);
  WRITEB(s0, 0);
  WRITEB(s1, 1);
  asm volatile("s_waitcnt lgkmcnt(0)");
  __builtin_amdgcn_sched_barrier(0);
  __builtin_amdgcn_s_barrier();
  __builtin_amdgcn_sched_barrier(0);

#pragma unroll 1
  for (int t = 0; t < 30; t += 3) {
    ITER(t + 0, s0, 0, s2, 2);
    ITER(t + 1, s1, 1, s0, 0);
    ITER(t + 2, s2, 2, s1, 1);
  }
  // tail: tiles 30 (buf0, written at t=28) and 31 (buf1, written at t=29) — already visible.
  COMPUTE(0);
  COMPUTE(1);

#undef LOADB
#undef WRITEB
#undef COMPUTE
#undef ITER

  float vj[4], cbj[4];
#pragma unroll
  for (int j2 = 0; j2 < 4; ++j2) {
    int col = n0 + wn * 64 + j2 * 16 + l16;
    vj[j2] = v[col];
    // sum the 4 e-quarter partials (L2-hot, 98KB table); biases folded into quarter 0
    cbj[j2] = ctxb_q[head * A + col] + ctxb_q[3 * A + head * A + col] +
              ctxb_q[6 * A + head * A + col] + ctxb_q[9 * A + head * A + col];
  }
#pragma unroll
  for (int i = 0; i < 2; ++i) {
#pragma unroll
    for (int r = 0; r < 4; ++r) {
      float p = 0.f;
#pragma unroll
      for (int j2 = 0; j2 < 4; ++j2) {
        float u = acc[i][j2][r] + cbj[j2];
        float ex = __expf(2.f * u);        // tanh = 1 - 2/(e^2x+1); inf-safe at both ends
        float th = 1.f - 2.f / (ex + 1.f);
        p = fmaf(th, vj[j2], p);
      }
      p += __shfl_xor(p, 1);
      p += __shfl_xor(p, 2);
      p += __shfl_xor(p, 4);
      p += __shfl_xor(p, 8);
      if (l16 == 0) atomicAdd(&e_part[wm * 32 + i * 16 + quad * 4 + r], p);
    }
  }
  __syncthreads();
  if (tid < 64) atomicAdd(&e_h[m0 + tid], e_part[tid]);
}

// ---------- softmax stats per head (max, sum) over s < len ----------
__global__ void k_stats(const float* __restrict__ e_arr, const int* __restrict__ length,
                        float* __restrict__ stats) {
  int head = blockIdx.x;
  const float* e_h = e_arr + head * S;
  int len = min(max(length[0], 0), S);
  int tid = threadIdx.x;
  __shared__ float red[4];
  __shared__ float bmax;

  float m = -3.4e38f;
  for (int s = tid; s < len; s += 256) m = fmaxf(m, e_h[s]);
#pragma unroll
  for (int o = 32; o >= 1; o >>= 1) m = fmaxf(m, __shfl_xor(m, o));
  if ((tid & 63) == 0) red[tid >> 6] = m;
  __syncthreads();
  if (tid == 0) bmax = fmaxf(fmaxf(red[0], red[1]), fmaxf(red[2], red[3]));
  __syncthreads();
  float mm = bmax;

  float ss = 0.f;
  for (int s = tid; s < len; s += 256) ss += __expf(e_h[s] - mm);
#pragma unroll
  for (int o = 32; o >= 1; o >>= 1) ss += __shfl_xor(ss, o);
  __syncthreads();
  if ((tid & 63) == 0) red[tid >> 6] = ss;
  __syncthreads();
  if (tid == 0) {
    stats[head * 2 + 0] = mm;
    stats[head * 2 + 1] = red[0] + red[1] + red[2] + red[3];
  }
}

// ---------- out[h] = sum_s w(s) * sentence[s][h], w from e+stats (no redundant stats) ----------
__global__ void k_out(const float* __restrict__ sent, const float* __restrict__ e_arr,
                      const float* __restrict__ stats, const int* __restrict__ length,
                      float* __restrict__ out) {
  int len = min(max(length[0], 0), S);
  int r0 = blockIdx.x * 16;
  if (r0 >= len) return;
  int tid = threadIdx.x;

  __shared__ float wrow[16];
  if (tid < 16 && r0 + tid < len) {
    int r = r0 + tid;
    wrow[tid] = (__expf(e_arr[r] - stats[0]) / stats[1] +
                 __expf(e_arr[S + r] - stats[2]) / stats[3] +
                 __expf(e_arr[2 * S + r] - stats[4]) / stats[5]) * (1.f / 3.f);
  }
  __syncthreads();

  int col = tid * 4;
  int rend = min(r0 + 16, len);
  float4 acc = {0.f, 0.f, 0.f, 0.f};
  for (int r = r0; r < rend; ++r) {
    float w = wrow[r - r0];
    float4 x = *(const float4*)(sent + (size_t)r * H + col);
    acc.x = fmaf(w, x.x, acc.x);
    acc.y = fmaf(w, x.y, acc.y);
    acc.z = fmaf(w, x.z, acc.z);
    acc.w = fmaf(w, x.w, acc.w);
  }
  atomicAdd(&out[col + 0], acc.x);
  atomicAdd(&out[col + 1], acc.y);
  atomicAdd(&out[col + 2], acc.z);
  atomicAdd(&out[col + 3], acc.w);
}

}  // namespace

extern "C" void kernel_launch(void* const* d_in, const int* in_sizes, int n_in,
                              void* d_out, int out_size, void* d_ws, size_t ws_size,
                              hipStream_t stream) {
  const float* sentence = (const float*)d_in[0];
  const int* length     = (const int*)d_in[1];
  const float* ctx_p = (const float*)d_in[2];
  const float* ctx_c = (const float*)d_in[3];
  const float* ctx_h = (const float*)d_in[4];
  const float* W_s[3] = {(const float*)d_in[5],  (const float*)d_in[11], (const float*)d_in[17]};
  const float* b_s[3] = {(const float*)d_in[6],  (const float*)d_in[12], (const float*)d_in[18]};
  const float* W_c[3] = {(const float*)d_in[7],  (const float*)d_in[13], (const float*)d_in[19]};
  const float* b_c[3] = {(const float*)d_in[8],  (const float*)d_in[14], (const float*)d_in[20]};
  const float* v_[3]  = {(const float*)d_in[9],  (const float*)d_in[15], (const float*)d_in[21]};
  float* out = (float*)d_out;

  // workspace layout (bytes)
  char* ws = (char*)d_ws;
  __bf16* sentB  = (__bf16*)(ws);               // 8192*1024*2   = 16777216
  __bf16* WtB    = (__bf16*)(ws + 16777216);    // 3*2048*1024*2 = 12582912
  float* ctxb_q  = (float*)(ws + 29360128);     // 4*3*2048*4    = 98304
  float* e_arr   = (float*)(ws + 29458432);     // 3*8192*4      = 98304
  float* stats   = (float*)(ws + 29556736);     // 6 floats

  // 4 graph nodes, no memsets, no cross-kernel atomics except e_arr/out (zeroed in prep).
  k_prep<<<5736, 256, 0, stream>>>(sentence, sentB,
                                   W_s[0], W_s[1], W_s[2], WtB,
                                   ctx_p, ctx_c, ctx_h,
                                   W_c[0], W_c[1], W_c[2],
                                   b_s[0], b_s[1], b_s[2],
                                   b_c[0], b_c[1], b_c[2], ctxb_q, e_arr,
                                   length, out, out_size);
  k_gemm_e<<<6144, 256, 0, stream>>>(sentB, WtB, ctxb_q,
                                     v_[0], v_[1], v_[2], length, e_arr);
  k_stats<<<3, 256, 0, stream>>>(e_arr, length, stats);
  k_out<<<S / 16, 256, 0, stream>>>(sentence, e_arr, stats, length, out);
}